// Round 3
// baseline (505.570 us; speedup 1.0000x reference)
//
#include <hip/hip_runtime.h>
#include <hip/hip_bf16.h>

#define Bq 4
#define Nq 4096
#define Dq 64
#define Mq 64

typedef float f4 __attribute__((ext_vector_type(4)));
typedef short s16x8 __attribute__((ext_vector_type(8)));

// ---- ws layout (offsets in FLOATS) ----
#define PINVTH_OFF 16384     // [B][64][64] bf16 hi (pinv^T, [n][k])  8192 f
#define PINVTL_OFF 24576     // [B][64][64] bf16 lo                   8192 f
#define PMAX_OFF   33024     // [B][64][64] per-slice col max  16384 f
#define PSUM_OFF   49408     // [B][64][64] per-slice col sum  16384 f
#define K1H_OFF    164608    // [B][N][M] bf16 hi   524288 f (1M shorts)
#define K1L_OFF    688896    // [B][N][M] bf16 lo   524288 f
#define L3_OFF     1213184   // [B][N][M] fp32 raw logits 1048576 f

#define NS 72  // LDS row stride (shorts) for NS matrices: 144 B rows, 16B-aligned

__device__ __forceinline__ float wave_max(float v) {
#pragma unroll
  for (int off = 32; off > 0; off >>= 1) v = fmaxf(v, __shfl_xor(v, off, 64));
  return v;
}
__device__ __forceinline__ float wave_sum(float v) {
#pragma unroll
  for (int off = 32; off > 0; off >>= 1) v += __shfl_xor(v, off, 64);
  return v;
}
__device__ __forceinline__ short f2bf(float x) {  // RNE fp32->bf16
  unsigned u = __float_as_uint(x);
  unsigned r = (u + 0x7fffu + ((u >> 16) & 1u)) >> 16;
  return (short)r;
}
__device__ __forceinline__ float bf2f(short h) {
  return __uint_as_float(((unsigned)(unsigned short)h) << 16);
}

// Split-bf16 MFMA 64x64x64: Z rows [w*16,+16) x all 64 cols.
// X in A-layout [m][k] (stride NS), Y^T in B-layout [n][k] (stride NS).
__device__ __forceinline__ void ns_mm(const short* Xh, const short* Xl,
                                      const short* YTh, const short* YTl,
                                      int w, int lane, f4 z[4]) {
  const int q = lane >> 4, cl = lane & 15;
  const int ar = (w * 16 + cl) * NS + q * 8;
  const s16x8 ah0 = *(const s16x8*)&Xh[ar];
  const s16x8 ah1 = *(const s16x8*)&Xh[ar + 32];
  const s16x8 al0 = *(const s16x8*)&Xl[ar];
  const s16x8 al1 = *(const s16x8*)&Xl[ar + 32];
#pragma unroll
  for (int ct = 0; ct < 4; ++ct) {
    const int br = (ct * 16 + cl) * NS + q * 8;
    const s16x8 bh0 = *(const s16x8*)&YTh[br];
    const s16x8 bh1 = *(const s16x8*)&YTh[br + 32];
    const s16x8 bl0 = *(const s16x8*)&YTl[br];
    const s16x8 bl1 = *(const s16x8*)&YTl[br + 32];
    f4 acc = {0.f, 0.f, 0.f, 0.f};
    acc = __builtin_amdgcn_mfma_f32_16x16x32_bf16(ah0, bh0, acc, 0, 0, 0);
    acc = __builtin_amdgcn_mfma_f32_16x16x32_bf16(ah1, bh1, acc, 0, 0, 0);
    acc = __builtin_amdgcn_mfma_f32_16x16x32_bf16(al0, bh0, acc, 0, 0, 0);
    acc = __builtin_amdgcn_mfma_f32_16x16x32_bf16(al1, bh1, acc, 0, 0, 0);
    acc = __builtin_amdgcn_mfma_f32_16x16x32_bf16(ah0, bl0, acc, 0, 0, 0);
    acc = __builtin_amdgcn_mfma_f32_16x16x32_bf16(ah1, bl1, acc, 0, 0, 0);
    z[ct] = acc;
  }
}

// Row work for one 64-row slice rb: kernel1 softmax rows + kernel3 raw logits
// + per-slice column stats (4 waves merged via LDS -> one partial per slice).
__device__ __forceinline__ void row_work(const float* __restrict__ Q,
                                         const float* __restrict__ K,
                                         const int* __restrict__ idx_q,
                                         const int* __restrict__ idx_k,
                                         float* __restrict__ ws, int rb,
                                         int lane, int w, float* lds) {
  const int b = rb >> 6, rbi = rb & 63;
  const int myiq = idx_q[lane], myik = idx_k[lane];
  const float* qg = Q + ((size_t)b * Nq + myiq) * 64;
  const float* kg = K + ((size_t)b * Nq + myik) * 64;
  f4 qcol[16], kcol[16];  // Qt[lane][:], Kt[lane][:]
#pragma unroll
  for (int j = 0; j < 16; ++j) {
    qcol[j] = *(const f4*)(qg + j * 4);
    kcol[j] = *(const f4*)(kg + j * 4);
  }
  short* k1h = (short*)(ws + K1H_OFF);
  short* k1l = (short*)(ws + K1L_OFF);
  float runmax = -INFINITY, runsum = 0.f;
  const int nbase = __builtin_amdgcn_readfirstlane(rbi * 64 + w * 16);
  for (int rr = 0; rr < 16; ++rr) {
    const int n = nbase + rr;
    const float* qrow = Q + ((size_t)b * Nq + n) * 64;  // wave-uniform
    const float* krow = K + ((size_t)b * Nq + n) * 64;
    float acc1 = 0.f, acc3 = 0.f;
#pragma unroll
    for (int j = 0; j < 16; ++j) {
      f4 qv = *(const f4*)(qrow + j * 4);
      f4 kv = *(const f4*)(krow + j * 4);
#pragma unroll
      for (int u = 0; u < 4; ++u) {
        acc1 = fmaf(qv[u], kcol[j][u], acc1);  // kernel1 logit
        acc3 = fmaf(kv[u], qcol[j][u], acc3);  // kernel3 logit
      }
    }
    float mx = wave_max(acc1);
    float e = __expf(acc1 - mx);
    float s = wave_sum(e);
    float p = e / s;
    const size_t oidx = ((size_t)(b * Nq + n)) * 64 + lane;
    short h = f2bf(p);
    k1h[oidx] = h;
    k1l[oidx] = f2bf(p - bf2f(h));
    ws[L3_OFF + oidx] = acc3;
    float nm = fmaxf(runmax, acc3);
    runsum = runsum * __expf(runmax - nm) + __expf(acc3 - nm);
    runmax = nm;
  }
  // merge the 4 waves' online stats -> one partial per slice
  lds[w * 64 + lane] = runmax;
  lds[256 + w * 64 + lane] = runsum;
  __syncthreads();
  if (w == 0) {
    float fm = lds[lane];
#pragma unroll
    for (int g = 1; g < 4; ++g) fm = fmaxf(fm, lds[g * 64 + lane]);
    float fs = 0.f;
#pragma unroll
    for (int g = 0; g < 4; ++g)
      fs += lds[256 + g * 64 + lane] * __expf(lds[g * 64 + lane] - fm);
    ws[PMAX_OFF + (b * 64 + rbi) * 64 + lane] = fm;
    ws[PSUM_OFF + (b * 64 + rbi) * 64 + lane] = fs;
  }
  __syncthreads();  // allow LDS reuse by a second slice
}

// ------------- main: 256 blocks. Blocks 0..3: K2 + gmax + Newton-Schulz ONLY
// (overlaps with row work on the other 252 blocks). Blocks 4..255: one row
// slice each; blocks 4..7 take the 4 leftover slices as a second pass. -------
__global__ __launch_bounds__(256) void k_main(const float* __restrict__ Q,
                                              const float* __restrict__ K,
                                              const int* __restrict__ idx_q,
                                              const int* __restrict__ idx_k,
                                              float* __restrict__ ws) {
  __shared__ short nsm[14 * 64 * NS];  // 129 KB: 14 bf16 64x64 matrices
  const int t = threadIdx.x;
  const int lane = t & 63, w = t >> 6;
  if (blockIdx.x >= Bq) {
    float* lds = (float*)nsm;
    row_work(Q, K, idx_q, idx_k, ws, blockIdx.x - Bq, lane, w, lds);
    if (blockIdx.x < 2 * Bq)
      row_work(Q, K, idx_q, idx_k, ws, 252 + (blockIdx.x - Bq), lane, w, lds);
    return;
  }
  // ---------------- prep (K2 + gmax) + Newton-Schulz: blocks 0..3 ----------------
  const int b = blockIdx.x;
  const int q = lane >> 4, cl = lane & 15;
  short* A2h = nsm + 0 * 4608;   short* A2l = nsm + 1 * 4608;   // A2 [m][k]
  short* Vh  = nsm + 2 * 4608;   short* Vl  = nsm + 3 * 4608;   // V [m][k]
  short* VTh = nsm + 4 * 4608;   short* VTl = nsm + 5 * 4608;   // V^T [n][k]
  short* Ph  = nsm + 6 * 4608;   short* Pl  = nsm + 7 * 4608;   // P [m][k]
  short* PTh = nsm + 8 * 4608;   short* PTl = nsm + 9 * 4608;   // P^T [n][k]
  short* Wbh = nsm + 10 * 4608;  short* Wbl = nsm + 11 * 4608;  // W (B-layout)
  short* W2h = nsm + 12 * 4608;  short* W2l = nsm + 13 * 4608;  // W2 (B-layout)
  // prep staging aliases (dead before NS loop uses the same slots)
  short* Qsh = Ph;   short* Qsl = Pl;    // Qt split-bf16, A-layout [m][d]
  short* Ksh = PTh;  short* Ksl = PTl;   // Kt split-bf16, B-layout [n][d]
  float* csum = (float*)Wbh;             // [4][64] per-wave column sums
  float* gacc = (float*)W2h;             // running global max
  if (t == 0) *gacc = -INFINITY;
  f4 z[4];
  f4 pown[4];  // own batch's K2 fragment (rows w*16+q*4+i, cols ct*16+cl)
  // prefetched landmark-row registers (batch bb)
  const int gr = t >> 2, seg = (t & 3) * 16;
  const int iqr = idx_q[gr], ikr = idx_k[gr];
  const float* qbase = Q + (size_t)iqr * 64 + seg;
  const float* kbase = K + (size_t)ikr * 64 + seg;
  f4 qv[4], kv[4];
#pragma unroll
  for (int j = 0; j < 4; ++j) {  // batch 0 gather
    qv[j] = *(const f4*)(qbase + j * 4);
    kv[j] = *(const f4*)(kbase + j * 4);
  }
  for (int bb = 0; bb < Bq; ++bb) {
    __syncthreads();  // prior readers of Qs/Ks/csum done (also covers gacc init)
    {  // stage prefetched rows, convert to split-bf16
#pragma unroll
      for (int j = 0; j < 4; ++j)
#pragma unroll
        for (int u = 0; u < 4; ++u) {
          const int c = seg + j * 4 + u;
          short qh = f2bf(qv[j][u]);
          Qsh[gr * NS + c] = qh;
          Qsl[gr * NS + c] = f2bf(qv[j][u] - bf2f(qh));
          short kh = f2bf(kv[j][u]);
          Ksh[gr * NS + c] = kh;
          Ksl[gr * NS + c] = f2bf(kv[j][u] - bf2f(kh));
        }
      if (bb < Bq - 1) {  // issue next batch's gather (overlaps mm+softmax)
        const float* qn = qbase + (size_t)(bb + 1) * Nq * 64;
        const float* kn = kbase + (size_t)(bb + 1) * Nq * 64;
#pragma unroll
        for (int j = 0; j < 4; ++j) {
          qv[j] = *(const f4*)(qn + j * 4);
          kv[j] = *(const f4*)(kn + j * 4);
        }
      }
    }
    __syncthreads();
    ns_mm(Qsh, Qsl, Ksh, Ksl, w, lane, z);  // logits[m][n], fp32-grade
    // row softmax: row = w*16+q*4+i lives in the 16 lanes sharing q (cl=0..15)
    f4 pz[4];
#pragma unroll
    for (int i = 0; i < 4; ++i) {
      float m = fmaxf(fmaxf(z[0][i], z[1][i]), fmaxf(z[2][i], z[3][i]));
#pragma unroll
      for (int off = 8; off > 0; off >>= 1) m = fmaxf(m, __shfl_xor(m, off, 64));
      float e0 = __expf(z[0][i] - m), e1 = __expf(z[1][i] - m);
      float e2 = __expf(z[2][i] - m), e3 = __expf(z[3][i] - m);
      float s = e0 + e1 + e2 + e3;
#pragma unroll
      for (int off = 8; off > 0; off >>= 1) s += __shfl_xor(s, off, 64);
      float inv = 1.0f / s;
      pz[0][i] = e0 * inv; pz[1][i] = e1 * inv;
      pz[2][i] = e2 * inv; pz[3][i] = e3 * inv;
    }
    if (bb == b) {
#pragma unroll
      for (int ct = 0; ct < 4; ++ct) pown[ct] = pz[ct];
    }
    // column sums (axis=-2): reduce rows over i then over q (lanes ^16, ^32)
#pragma unroll
    for (int ct = 0; ct < 4; ++ct) {
      float cp = pz[ct][0] + pz[ct][1] + pz[ct][2] + pz[ct][3];
      cp += __shfl_xor(cp, 16, 64);
      cp += __shfl_xor(cp, 32, 64);
      if (q == 0) csum[w * 64 + ct * 16 + cl] = cp;
    }
    __syncthreads();
    if (t < 64) {  // wave 0: combine 4 waves, track global max
      float tot = csum[t] + csum[64 + t] + csum[128 + t] + csum[192 + t];
      float mcol = wave_max(tot);
      if (t == 0) *gacc = fmaxf(*gacc, mcol);
    }
  }
  __syncthreads();
  const float inv_g = 1.0f / *gacc;
  {  // init: A2 = k2 (A-layout); V = A2^T/g (A-layout + B-layout)
#pragma unroll
    for (int ct = 0; ct < 4; ++ct)
#pragma unroll
      for (int i = 0; i < 4; ++i) {
        const int row = w * 16 + q * 4 + i, c = ct * 16 + cl;
        float a2 = pown[ct][i];
        short h = f2bf(a2);
        A2h[row * NS + c] = h;
        A2l[row * NS + c] = f2bf(a2 - bf2f(h));
        float vv = a2 * inv_g;
        short vh = f2bf(vv), vl = f2bf(vv - bf2f(vh));
        VTh[row * NS + c] = vh;  // VT[n=row][k=c] = A2[row][c]/g
        VTl[row * NS + c] = vl;
        Vh[c * NS + row] = vh;   // V[m=c][k=row] = A2[row][c]/g
        Vl[c * NS + row] = vl;
      }
  }
  __syncthreads();
  for (int it = 0; it < 6; ++it) {
    // 1: P = A2 @ V
    ns_mm(A2h, A2l, VTh, VTl, w, lane, z);
#pragma unroll
    for (int ct = 0; ct < 4; ++ct)
#pragma unroll
      for (int i = 0; i < 4; ++i) {
        const int row = w * 16 + q * 4 + i, c = ct * 16 + cl;
        float vv = z[ct][i];
        short h = f2bf(vv), l = f2bf(vv - bf2f(h));
        Ph[row * NS + c] = h;  Pl[row * NS + c] = l;
        PTh[c * NS + row] = h; PTl[c * NS + row] = l;
      }
    __syncthreads();
    // 2: W = 7P - P@P  (B-layout only)
    ns_mm(Ph, Pl, PTh, PTl, w, lane, z);
#pragma unroll
    for (int ct = 0; ct < 4; ++ct)
#pragma unroll
      for (int i = 0; i < 4; ++i) {
        const int row = w * 16 + q * 4 + i, c = ct * 16 + cl;
        float pf = bf2f(Ph[row * NS + c]) + bf2f(Pl[row * NS + c]);
        float vv = 7.f * pf - z[ct][i];
        short h = f2bf(vv);
        Wbh[c * NS + row] = h; Wbl[c * NS + row] = f2bf(vv - bf2f(h));
      }
    __syncthreads();
    // 3: W2 = 15P - P@W  (B-layout only)
    ns_mm(Ph, Pl, Wbh, Wbl, w, lane, z);
#pragma unroll
    for (int ct = 0; ct < 4; ++ct)
#pragma unroll
      for (int i = 0; i < 4; ++i) {
        const int row = w * 16 + q * 4 + i, c = ct * 16 + cl;
        float pf = bf2f(Ph[row * NS + c]) + bf2f(Pl[row * NS + c]);
        float vv = 15.f * pf - z[ct][i];
        short h = f2bf(vv);
        W2h[c * NS + row] = h; W2l[c * NS + row] = f2bf(vv - bf2f(h));
      }
    __syncthreads();
    // 4: V = 0.25*(13V - V@W2)  (A-layout + B-layout, in place)
    ns_mm(Vh, Vl, W2h, W2l, w, lane, z);
#pragma unroll
    for (int ct = 0; ct < 4; ++ct)
#pragma unroll
      for (int i = 0; i < 4; ++i) {
        const int row = w * 16 + q * 4 + i, c = ct * 16 + cl;
        float vf = bf2f(Vh[row * NS + c]) + bf2f(Vl[row * NS + c]);
        float vv = 0.25f * (13.f * vf - z[ct][i]);
        short h = f2bf(vv), l = f2bf(vv - bf2f(h));
        Vh[row * NS + c] = h;  Vl[row * NS + c] = l;
        VTh[c * NS + row] = h; VTl[c * NS + row] = l;
      }
    __syncthreads();
  }
  {  // epilogue: pinv^T (=VT) hi/lo -> ws, compact [n][k] stride 64
    const int r = t >> 2, c0 = (t & 3) * 16;
    short* gh = (short*)(ws + PINVTH_OFF) + b * 4096;
    short* gl = (short*)(ws + PINVTL_OFF) + b * 4096;
#pragma unroll
    for (int i = 0; i < 16; ++i) {
      gh[r * 64 + c0 + i] = VTh[r * NS + c0 + i];
      gl[r * 64 + c0 + i] = VTl[r * NS + c0 + i];
    }
  }
}

// ------- final: colstats (per-block, cheap) -> T = k1@pinv*cinv -> T @ exp(L3-cm) -------
// grid 1024 = B(4) x row-tile(64) x col-chunk(4). K3 computed on the fly.
__global__ __launch_bounds__(256) void k_final(const float* __restrict__ ws,
                                               float* __restrict__ out) {
  __shared__ short tbh[4096];  // T hi, row-major 64x64
  __shared__ short tbl[4096];  // T lo
  __shared__ float smax[4][64], ssum[4][64];
  __shared__ float cmS[64], ciS[64];
  const int t = threadIdx.x;
  const int gx = blockIdx.x;
  const int b = gx >> 8;
  const int rem = gx & 255;
  const int rt = rem >> 2;  // row tile 0..63
  const int ch = rem & 3;   // col chunk 0..3 (1024 cols each)
  const int r0 = rt * 64;
  const int w = t >> 6, lane = t & 63;
  const int q = lane >> 4, cl = lane & 15;
  {  // colstats for batch b: merge 64 per-slice partials (4 groups x 16)
    const int m = t & 63, g = t >> 6;
    float rm = -INFINITY, rs = 0.f;
#pragma unroll 4
    for (int i = 0; i < 16; ++i) {
      int slot = g * 16 + i;
      float pm = ws[PMAX_OFF + (b * 64 + slot) * 64 + m];
      float ps = ws[PSUM_OFF + (b * 64 + slot) * 64 + m];
      float nm = fmaxf(rm, pm);
      rs = rs * __expf(rm - nm) + ps * __expf(pm - nm);
      rm = nm;
    }
    smax[g][m] = rm;
    ssum[g][m] = rs;
  }
  __syncthreads();
  if (t < 64) {
    float fm = smax[0][t];
    for (int g2 = 1; g2 < 4; ++g2) fm = fmaxf(fm, smax[g2][t]);
    float fs = 0.f;
    for (int g2 = 0; g2 < 4; ++g2) fs += ssum[g2][t] * __expf(smax[g2][t] - fm);
    cmS[t] = fm;
    ciS[t] = 1.0f / fs;
  }
  __syncthreads();
  {  // Phase A: T rows [w*16,+16) = (k1_tile @ pinv) * cinv[col], split-bf16
    const short* k1h = (const short*)(ws + K1H_OFF);
    const short* k1l = (const short*)(ws + K1L_OFF);
    const size_t ar = ((size_t)(b * Nq + r0 + w * 16 + cl)) * 64 + q * 8;
    const s16x8 ah0 = *(const s16x8*)&k1h[ar];
    const s16x8 ah1 = *(const s16x8*)&k1h[ar + 32];
    const s16x8 al0 = *(const s16x8*)&k1l[ar];
    const s16x8 al1 = *(const s16x8*)&k1l[ar + 32];
    const short* pth = (const short*)(ws + PINVTH_OFF) + b * 4096;
    const short* ptl = (const short*)(ws + PINVTL_OFF) + b * 4096;
#pragma unroll
    for (int ct = 0; ct < 4; ++ct) {
      const int br = (ct * 16 + cl) * 64 + q * 8;
      const s16x8 bh0 = *(const s16x8*)&pth[br];
      const s16x8 bh1 = *(const s16x8*)&pth[br + 32];
      const s16x8 bl0 = *(const s16x8*)&ptl[br];
      const s16x8 bl1 = *(const s16x8*)&ptl[br + 32];
      f4 acc = {0.f, 0.f, 0.f, 0.f};
      acc = __builtin_amdgcn_mfma_f32_16x16x32_bf16(ah0, bh0, acc, 0, 0, 0);
      acc = __builtin_amdgcn_mfma_f32_16x16x32_bf16(ah1, bh1, acc, 0, 0, 0);
      acc = __builtin_amdgcn_mfma_f32_16x16x32_bf16(al0, bh0, acc, 0, 0, 0);
      acc = __builtin_amdgcn_mfma_f32_16x16x32_bf16(al1, bh1, acc, 0, 0, 0);
      acc = __builtin_amdgcn_mfma_f32_16x16x32_bf16(ah0, bl0, acc, 0, 0, 0);
      acc = __builtin_amdgcn_mfma_f32_16x16x32_bf16(ah1, bl1, acc, 0, 0, 0);
      const int c = ct * 16 + cl;
      const float ci = ciS[c];
#pragma unroll
      for (int i = 0; i < 4; ++i) {
        const int row = w * 16 + q * 4 + i;
        float v = acc[i] * ci;  // fold 1/csum[m=c] into T column
        short h = f2bf(v);
        tbh[row * 64 + c] = h;
        tbl[row * 64 + c] = f2bf(v - bf2f(h));
      }
    }
  }
  __syncthreads();
  // Phase B: B-operand = exp(L3 - cm) computed on the fly, split-bf16 MFMA
  const s16x8 a0h = *(const s16x8*)&tbh[(w * 16 + cl) * 64 + q * 8];
  const s16x8 a1h = *(const s16x8*)&tbh[(w * 16 + cl) * 64 + q * 8 + 32];
  const s16x8 a0l = *(const s16x8*)&tbl[(w * 16 + cl) * 64 + q * 8];
  const s16x8 a1l = *(const s16x8*)&tbl[(w * 16 + cl) * 64 + q * 8 + 32];
  float cmr[16];  // cm for this lane's m indices: q*8+j and q*8+32+j
#pragma unroll
  for (int j = 0; j < 8; ++j) {
    cmr[j] = cmS[q * 8 + j];
    cmr[8 + j] = cmS[q * 8 + 32 + j];
  }
  const float* l3p =
      ws + L3_OFF + (((size_t)b * Nq + ch * 1024 + cl) * 64 + q * 8);
  float* outb = out + ((size_t)(b * Nq + r0 + w * 16)) * Nq;
  f4 x0 = *(const f4*)l3p;
  f4 x1 = *(const f4*)(l3p + 4);
  f4 x2 = *(const f4*)(l3p + 32);
  f4 x3 = *(const f4*)(l3p + 36);
  for (int nt = 0; nt < 64; ++nt) {
    f4 c0 = x0, c1 = x1, c2 = x2, c3 = x3;
    if (nt < 63) {
      const float* np = l3p + (size_t)(nt + 1) * 1024;
      x0 = *(const f4*)np;
      x1 = *(const f4*)(np + 4);
      x2 = *(const f4*)(np + 32);
      x3 = *(const f4*)(np + 36);
    }
    s16x8 bh0, bl0, bh1, bl1;
#pragma unroll
    for (int j = 0; j < 4; ++j) {
      float e;
      short h;
      e = __expf(c0[j] - cmr[j]);          h = f2bf(e);
      bh0[j] = h;      bl0[j] = f2bf(e - bf2f(h));
      e = __expf(c1[j] - cmr[4 + j]);      h = f2bf(e);
      bh0[4 + j] = h;  bl0[4 + j] = f2bf(e - bf2f(h));
      e = __expf(c2[j] - cmr[8 + j]);      h = f2bf(e);
      bh1[j] = h;      bl1[j] = f2bf(e - bf2f(h));
      e = __expf(c3[j] - cmr[12 + j]);     h = f2bf(e);
      bh1[4 + j] = h;  bl1[4 + j] = f2bf(e - bf2f(h));
    }
    f4 acc = {0.f, 0.f, 0.f, 0.f};
    acc = __builtin_amdgcn_mfma_f32_16x16x32_bf16(a0h, bh0, acc, 0, 0, 0);
    acc = __builtin_amdgcn_mfma_f32_16x16x32_bf16(a1h, bh1, acc, 0, 0, 0);
    acc = __builtin_amdgcn_mfma_f32_16x16x32_bf16(a0l, bh0, acc, 0, 0, 0);
    acc = __builtin_amdgcn_mfma_f32_16x16x32_bf16(a1l, bh1, acc, 0, 0, 0);
    acc = __builtin_amdgcn_mfma_f32_16x16x32_bf16(a0h, bl0, acc, 0, 0, 0);
    acc = __builtin_amdgcn_mfma_f32_16x16x32_bf16(a1h, bl1, acc, 0, 0, 0);
    const int ncol = ch * 1024 + nt * 16 + cl;
    float* op = outb + (size_t)(q * 4) * Nq + ncol;
#pragma unroll
    for (int i = 0; i < 4; ++i) op[(size_t)i * Nq] = acc[i];  // row=q*4+i
  }
}

extern "C" void kernel_launch(void* const* d_in, const int* in_sizes, int n_in,
                              void* d_out, int out_size, void* d_ws,
                              size_t ws_size, hipStream_t stream) {
  const float* Q = (const float*)d_in[0];
  const float* K = (const float*)d_in[1];
  const int* iq = (const int*)d_in[2];
  const int* ik = (const int*)d_in[3];
  float* ws = (float*)d_ws;
  float* out = (float*)d_out;
  hipLaunchKernelGGL(k_main, dim3(256), dim3(256), 0, stream, Q, K, iq, ik, ws);
  hipLaunchKernelGGL(k_final, dim3(1024), dim3(256), 0, stream, ws, out);
}

// Round 4
// 493.373 us; speedup vs baseline: 1.0247x; 1.0247x over previous
//
#include <hip/hip_runtime.h>
#include <hip/hip_bf16.h>

#define Bq 4
#define Nq 4096
#define Dq 64
#define Mq 64

typedef float f4 __attribute__((ext_vector_type(4)));
typedef short s16x8 __attribute__((ext_vector_type(8)));

// ---- ws layout (offsets in FLOATS) ----
#define PINVTH_OFF 16384     // [B][64][64] bf16 hi (pinv^T, [n][k])  8192 f
#define PINVTL_OFF 24576     // [B][64][64] bf16 lo                   8192 f
#define PMAX_OFF   33024     // [B][64][64] per-slice col max  16384 f
#define PSUM_OFF   49408     // [B][64][64] per-slice col sum  16384 f
#define K1H_OFF    164608    // [B][N][M] bf16 hi   524288 f (1M shorts)
#define K1L_OFF    688896    // [B][N][M] bf16 lo   524288 f
#define L3_OFF     1213184   // [B][N][M] fp32 raw logits 1048576 f
#define K3H_OFF    2261760   // [B][N][M] bf16 hi   524288 f
#define K3L_OFF    2786048   // [B][N][M] bf16 lo   524288 f

#define NS 72  // LDS row stride (shorts) for NS matrices: 144 B rows, 16B-aligned

__device__ __forceinline__ float wave_max(float v) {
#pragma unroll
  for (int off = 32; off > 0; off >>= 1) v = fmaxf(v, __shfl_xor(v, off, 64));
  return v;
}
__device__ __forceinline__ float wave_sum(float v) {
#pragma unroll
  for (int off = 32; off > 0; off >>= 1) v += __shfl_xor(v, off, 64);
  return v;
}
__device__ __forceinline__ short f2bf(float x) {  // RNE fp32->bf16
  unsigned u = __float_as_uint(x);
  unsigned r = (u + 0x7fffu + ((u >> 16) & 1u)) >> 16;
  return (short)r;
}
__device__ __forceinline__ float bf2f(short h) {
  return __uint_as_float(((unsigned)(unsigned short)h) << 16);
}

// Split-bf16 MFMA 64x64x64: Z rows [w*16,+16) x all 64 cols.
// X in A-layout [m][k] (stride NS), Y^T in B-layout [n][k] (stride NS).
__device__ __forceinline__ void ns_mm(const short* Xh, const short* Xl,
                                      const short* YTh, const short* YTl,
                                      int w, int lane, f4 z[4]) {
  const int q = lane >> 4, cl = lane & 15;
  const int ar = (w * 16 + cl) * NS + q * 8;
  const s16x8 ah0 = *(const s16x8*)&Xh[ar];
  const s16x8 ah1 = *(const s16x8*)&Xh[ar + 32];
  const s16x8 al0 = *(const s16x8*)&Xl[ar];
  const s16x8 al1 = *(const s16x8*)&Xl[ar + 32];
#pragma unroll
  for (int ct = 0; ct < 4; ++ct) {
    const int br = (ct * 16 + cl) * NS + q * 8;
    const s16x8 bh0 = *(const s16x8*)&YTh[br];
    const s16x8 bh1 = *(const s16x8*)&YTh[br + 32];
    const s16x8 bl0 = *(const s16x8*)&YTl[br];
    const s16x8 bl1 = *(const s16x8*)&YTl[br + 32];
    f4 acc = {0.f, 0.f, 0.f, 0.f};
    acc = __builtin_amdgcn_mfma_f32_16x16x32_bf16(ah0, bh0, acc, 0, 0, 0);
    acc = __builtin_amdgcn_mfma_f32_16x16x32_bf16(ah1, bh1, acc, 0, 0, 0);
    acc = __builtin_amdgcn_mfma_f32_16x16x32_bf16(al0, bh0, acc, 0, 0, 0);
    acc = __builtin_amdgcn_mfma_f32_16x16x32_bf16(al1, bh1, acc, 0, 0, 0);
    acc = __builtin_amdgcn_mfma_f32_16x16x32_bf16(ah0, bl0, acc, 0, 0, 0);
    acc = __builtin_amdgcn_mfma_f32_16x16x32_bf16(ah1, bl1, acc, 0, 0, 0);
    z[ct] = acc;
  }
}

// Row work for one 64-row slice rb: kernel1 softmax rows + kernel3 raw logits
// + per-slice column stats (4 waves merged via LDS -> one partial per slice).
__device__ __forceinline__ void row_work(const float* __restrict__ Q,
                                         const float* __restrict__ K,
                                         const int* __restrict__ idx_q,
                                         const int* __restrict__ idx_k,
                                         float* __restrict__ ws, int rb,
                                         int lane, int w, float* lds) {
  const int b = rb >> 6, rbi = rb & 63;
  const int myiq = idx_q[lane], myik = idx_k[lane];
  const float* qg = Q + ((size_t)b * Nq + myiq) * 64;
  const float* kg = K + ((size_t)b * Nq + myik) * 64;
  f4 qcol[16], kcol[16];  // Qt[lane][:], Kt[lane][:]
#pragma unroll
  for (int j = 0; j < 16; ++j) {
    qcol[j] = *(const f4*)(qg + j * 4);
    kcol[j] = *(const f4*)(kg + j * 4);
  }
  short* k1h = (short*)(ws + K1H_OFF);
  short* k1l = (short*)(ws + K1L_OFF);
  float runmax = -INFINITY, runsum = 0.f;
  const int nbase = __builtin_amdgcn_readfirstlane(rbi * 64 + w * 16);
  for (int rr = 0; rr < 16; ++rr) {
    const int n = nbase + rr;
    const float* qrow = Q + ((size_t)b * Nq + n) * 64;  // wave-uniform
    const float* krow = K + ((size_t)b * Nq + n) * 64;
    float acc1 = 0.f, acc3 = 0.f;
#pragma unroll
    for (int j = 0; j < 16; ++j) {
      f4 qv = *(const f4*)(qrow + j * 4);
      f4 kv = *(const f4*)(krow + j * 4);
#pragma unroll
      for (int u = 0; u < 4; ++u) {
        acc1 = fmaf(qv[u], kcol[j][u], acc1);  // kernel1 logit
        acc3 = fmaf(kv[u], qcol[j][u], acc3);  // kernel3 logit
      }
    }
    float mx = wave_max(acc1);
    float e = __expf(acc1 - mx);
    float s = wave_sum(e);
    float p = e / s;
    const size_t oidx = ((size_t)(b * Nq + n)) * 64 + lane;
    short h = f2bf(p);
    k1h[oidx] = h;
    k1l[oidx] = f2bf(p - bf2f(h));
    ws[L3_OFF + oidx] = acc3;
    float nm = fmaxf(runmax, acc3);
    runsum = runsum * __expf(runmax - nm) + __expf(acc3 - nm);
    runmax = nm;
  }
  // merge the 4 waves' online stats -> one partial per slice
  lds[w * 64 + lane] = runmax;
  lds[256 + w * 64 + lane] = runsum;
  __syncthreads();
  if (w == 0) {
    float fm = lds[lane];
#pragma unroll
    for (int g = 1; g < 4; ++g) fm = fmaxf(fm, lds[g * 64 + lane]);
    float fs = 0.f;
#pragma unroll
    for (int g = 0; g < 4; ++g)
      fs += lds[256 + g * 64 + lane] * __expf(lds[g * 64 + lane] - fm);
    ws[PMAX_OFF + (b * 64 + rbi) * 64 + lane] = fm;
    ws[PSUM_OFF + (b * 64 + rbi) * 64 + lane] = fs;
  }
  __syncthreads();  // allow LDS reuse by a second slice
}

// ------------- main: 256 blocks. Blocks 0..3: K2 + gmax + Newton-Schulz ONLY
// (overlaps with row work on the other 252 blocks). Blocks 4..255: one row
// slice each; blocks 4..7 take the 4 leftover slices as a second pass. -------
__global__ __launch_bounds__(256) void k_main(const float* __restrict__ Q,
                                              const float* __restrict__ K,
                                              const int* __restrict__ idx_q,
                                              const int* __restrict__ idx_k,
                                              float* __restrict__ ws) {
  __shared__ short nsm[14 * 64 * NS];  // 129 KB: 14 bf16 64x64 matrices
  const int t = threadIdx.x;
  const int lane = t & 63, w = t >> 6;
  if (blockIdx.x >= Bq) {
    float* lds = (float*)nsm;
    row_work(Q, K, idx_q, idx_k, ws, blockIdx.x - Bq, lane, w, lds);
    if (blockIdx.x < 2 * Bq)
      row_work(Q, K, idx_q, idx_k, ws, 252 + (blockIdx.x - Bq), lane, w, lds);
    return;
  }
  // ---------------- prep (K2 + gmax) + Newton-Schulz: blocks 0..3 ----------------
  const int b = blockIdx.x;
  const int q = lane >> 4, cl = lane & 15;
  short* A2h = nsm + 0 * 4608;   short* A2l = nsm + 1 * 4608;   // A2 [m][k]
  short* Vh  = nsm + 2 * 4608;   short* Vl  = nsm + 3 * 4608;   // V [m][k]
  short* VTh = nsm + 4 * 4608;   short* VTl = nsm + 5 * 4608;   // V^T [n][k]
  short* Ph  = nsm + 6 * 4608;   short* Pl  = nsm + 7 * 4608;   // P [m][k]
  short* PTh = nsm + 8 * 4608;   short* PTl = nsm + 9 * 4608;   // P^T [n][k]
  short* Wbh = nsm + 10 * 4608;  short* Wbl = nsm + 11 * 4608;  // W (B-layout)
  short* W2h = nsm + 12 * 4608;  short* W2l = nsm + 13 * 4608;  // W2 (B-layout)
  // prep staging aliases (dead before NS loop uses the same slots)
  short* Qsh = Ph;   short* Qsl = Pl;    // Qt split-bf16, A-layout [m][d]
  short* Ksh = PTh;  short* Ksl = PTl;   // Kt split-bf16, B-layout [n][d]
  float* csum = (float*)Wbh;             // [4][64] per-wave column sums
  float* gacc = (float*)W2h;             // running global max
  if (t == 0) *gacc = -INFINITY;
  f4 z[4];
  f4 pown[4];  // own batch's K2 fragment (rows w*16+q*4+i, cols ct*16+cl)
  // prefetched landmark-row registers (batch bb)
  const int gr = t >> 2, seg = (t & 3) * 16;
  const int iqr = idx_q[gr], ikr = idx_k[gr];
  const float* qbase = Q + (size_t)iqr * 64 + seg;
  const float* kbase = K + (size_t)ikr * 64 + seg;
  f4 qv[4], kv[4];
#pragma unroll
  for (int j = 0; j < 4; ++j) {  // batch 0 gather
    qv[j] = *(const f4*)(qbase + j * 4);
    kv[j] = *(const f4*)(kbase + j * 4);
  }
  for (int bb = 0; bb < Bq; ++bb) {
    __syncthreads();  // prior readers of Qs/Ks/csum done (also covers gacc init)
    {  // stage prefetched rows, convert to split-bf16
#pragma unroll
      for (int j = 0; j < 4; ++j)
#pragma unroll
        for (int u = 0; u < 4; ++u) {
          const int c = seg + j * 4 + u;
          short qh = f2bf(qv[j][u]);
          Qsh[gr * NS + c] = qh;
          Qsl[gr * NS + c] = f2bf(qv[j][u] - bf2f(qh));
          short kh = f2bf(kv[j][u]);
          Ksh[gr * NS + c] = kh;
          Ksl[gr * NS + c] = f2bf(kv[j][u] - bf2f(kh));
        }
      if (bb < Bq - 1) {  // issue next batch's gather (overlaps mm+softmax)
        const float* qn = qbase + (size_t)(bb + 1) * Nq * 64;
        const float* kn = kbase + (size_t)(bb + 1) * Nq * 64;
#pragma unroll
        for (int j = 0; j < 4; ++j) {
          qv[j] = *(const f4*)(qn + j * 4);
          kv[j] = *(const f4*)(kn + j * 4);
        }
      }
    }
    __syncthreads();
    ns_mm(Qsh, Qsl, Ksh, Ksl, w, lane, z);  // logits[m][n], fp32-grade
    // row softmax: row = w*16+q*4+i lives in the 16 lanes sharing q (cl=0..15)
    f4 pz[4];
#pragma unroll
    for (int i = 0; i < 4; ++i) {
      float m = fmaxf(fmaxf(z[0][i], z[1][i]), fmaxf(z[2][i], z[3][i]));
#pragma unroll
      for (int off = 8; off > 0; off >>= 1) m = fmaxf(m, __shfl_xor(m, off, 64));
      float e0 = __expf(z[0][i] - m), e1 = __expf(z[1][i] - m);
      float e2 = __expf(z[2][i] - m), e3 = __expf(z[3][i] - m);
      float s = e0 + e1 + e2 + e3;
#pragma unroll
      for (int off = 8; off > 0; off >>= 1) s += __shfl_xor(s, off, 64);
      float inv = 1.0f / s;
      pz[0][i] = e0 * inv; pz[1][i] = e1 * inv;
      pz[2][i] = e2 * inv; pz[3][i] = e3 * inv;
    }
    if (bb == b) {
#pragma unroll
      for (int ct = 0; ct < 4; ++ct) pown[ct] = pz[ct];
    }
    // column sums (axis=-2): reduce rows over i then over q (lanes ^16, ^32)
#pragma unroll
    for (int ct = 0; ct < 4; ++ct) {
      float cp = pz[ct][0] + pz[ct][1] + pz[ct][2] + pz[ct][3];
      cp += __shfl_xor(cp, 16, 64);
      cp += __shfl_xor(cp, 32, 64);
      if (q == 0) csum[w * 64 + ct * 16 + cl] = cp;
    }
    __syncthreads();
    if (t < 64) {  // wave 0: combine 4 waves, track global max
      float tot = csum[t] + csum[64 + t] + csum[128 + t] + csum[192 + t];
      float mcol = wave_max(tot);
      if (t == 0) *gacc = fmaxf(*gacc, mcol);
    }
  }
  __syncthreads();
  const float inv_g = 1.0f / *gacc;
  {  // init: A2 = k2 (A-layout); V = A2^T/g (A-layout + B-layout)
#pragma unroll
    for (int ct = 0; ct < 4; ++ct)
#pragma unroll
      for (int i = 0; i < 4; ++i) {
        const int row = w * 16 + q * 4 + i, c = ct * 16 + cl;
        float a2 = pown[ct][i];
        short h = f2bf(a2);
        A2h[row * NS + c] = h;
        A2l[row * NS + c] = f2bf(a2 - bf2f(h));
        float vv = a2 * inv_g;
        short vh = f2bf(vv), vl = f2bf(vv - bf2f(vh));
        VTh[row * NS + c] = vh;  // VT[n=row][k=c] = A2[row][c]/g
        VTl[row * NS + c] = vl;
        Vh[c * NS + row] = vh;   // V[m=c][k=row] = A2[row][c]/g
        Vl[c * NS + row] = vl;
      }
  }
  __syncthreads();
  for (int it = 0; it < 6; ++it) {
    // 1: P = A2 @ V
    ns_mm(A2h, A2l, VTh, VTl, w, lane, z);
#pragma unroll
    for (int ct = 0; ct < 4; ++ct)
#pragma unroll
      for (int i = 0; i < 4; ++i) {
        const int row = w * 16 + q * 4 + i, c = ct * 16 + cl;
        float vv = z[ct][i];
        short h = f2bf(vv), l = f2bf(vv - bf2f(h));
        Ph[row * NS + c] = h;  Pl[row * NS + c] = l;
        PTh[c * NS + row] = h; PTl[c * NS + row] = l;
      }
    __syncthreads();
    // 2: W = 7P - P@P  (B-layout only)
    ns_mm(Ph, Pl, PTh, PTl, w, lane, z);
#pragma unroll
    for (int ct = 0; ct < 4; ++ct)
#pragma unroll
      for (int i = 0; i < 4; ++i) {
        const int row = w * 16 + q * 4 + i, c = ct * 16 + cl;
        float pf = bf2f(Ph[row * NS + c]) + bf2f(Pl[row * NS + c]);
        float vv = 7.f * pf - z[ct][i];
        short h = f2bf(vv);
        Wbh[c * NS + row] = h; Wbl[c * NS + row] = f2bf(vv - bf2f(h));
      }
    __syncthreads();
    // 3: W2 = 15P - P@W  (B-layout only)
    ns_mm(Ph, Pl, Wbh, Wbl, w, lane, z);
#pragma unroll
    for (int ct = 0; ct < 4; ++ct)
#pragma unroll
      for (int i = 0; i < 4; ++i) {
        const int row = w * 16 + q * 4 + i, c = ct * 16 + cl;
        float pf = bf2f(Ph[row * NS + c]) + bf2f(Pl[row * NS + c]);
        float vv = 15.f * pf - z[ct][i];
        short h = f2bf(vv);
        W2h[c * NS + row] = h; W2l[c * NS + row] = f2bf(vv - bf2f(h));
      }
    __syncthreads();
    // 4: V = 0.25*(13V - V@W2)  (A-layout + B-layout, in place)
    ns_mm(Vh, Vl, W2h, W2l, w, lane, z);
#pragma unroll
    for (int ct = 0; ct < 4; ++ct)
#pragma unroll
      for (int i = 0; i < 4; ++i) {
        const int row = w * 16 + q * 4 + i, c = ct * 16 + cl;
        float vf = bf2f(Vh[row * NS + c]) + bf2f(Vl[row * NS + c]);
        float vv = 0.25f * (13.f * vf - z[ct][i]);
        short h = f2bf(vv), l = f2bf(vv - bf2f(h));
        Vh[row * NS + c] = h;  Vl[row * NS + c] = l;
        VTh[c * NS + row] = h; VTl[c * NS + row] = l;
      }
    __syncthreads();
  }
  {  // epilogue: pinv^T (=VT) hi/lo -> ws, compact [n][k] stride 64
    const int r = t >> 2, c0 = (t & 3) * 16;
    short* gh = (short*)(ws + PINVTH_OFF) + b * 4096;
    short* gl = (short*)(ws + PINVTL_OFF) + b * 4096;
#pragma unroll
    for (int i = 0; i < 16; ++i) {
      gh[r * 64 + c0 + i] = VTh[r * NS + c0 + i];
      gl[r * 64 + c0 + i] = VTl[r * NS + c0 + i];
    }
  }
}

// ------- colstats (per-block, 64 partials) + normalize -> K3 hi/lo bf16 -------
// 256 blocks x 256 threads; block's batch b = blockIdx.x >> 6.
__global__ __launch_bounds__(256) void k_norm(float* __restrict__ ws) {
  __shared__ float smax[4][64], ssum[4][64];
  __shared__ float cm[64], cinv[64];
  const int t = threadIdx.x;
  const int b = blockIdx.x >> 6;
  const int m = t & 63, g = t >> 6;
  // column stats for batch b: merge 64 per-slice partials (4 groups x 16)
  float rm = -INFINITY, rs = 0.f;
#pragma unroll 4
  for (int i = 0; i < 16; ++i) {
    int slot = g * 16 + i;
    float pm = ws[PMAX_OFF + (b * 64 + slot) * 64 + m];
    float ps = ws[PSUM_OFF + (b * 64 + slot) * 64 + m];
    float nm = fmaxf(rm, pm);
    rs = rs * __expf(rm - nm) + ps * __expf(pm - nm);
    rm = nm;
  }
  smax[g][m] = rm;
  ssum[g][m] = rs;
  __syncthreads();
  if (t < 64) {
    float fm = smax[0][t];
    for (int g2 = 1; g2 < 4; ++g2) fm = fmaxf(fm, smax[g2][t]);
    float fs = 0.f;
    for (int g2 = 0; g2 < 4; ++g2) fs += ssum[g2][t] * __expf(smax[g2][t] - fm);
    cm[t] = fm;
    cinv[t] = 1.0f / fs;
  }
  __syncthreads();
  short* k3h = (short*)(ws + K3H_OFF);
  short* k3l = (short*)(ws + K3L_OFF);
  const size_t base = (size_t)blockIdx.x * 4096;
  const float c1 = cm[t & 63], c2 = cinv[t & 63];
#pragma unroll 4
  for (int i = 0; i < 16; ++i) {
    size_t idx = base + (size_t)i * 256 + t;
    float v = __expf(ws[L3_OFF + idx] - c1) * c2;
    short h = f2bf(v);
    k3h[idx] = h;
    k3l[idx] = f2bf(v - bf2f(h));
  }
}

// ------- final: T = k1@pinv (MFMA split-bf16) then T @ K3 -> out -------
// grid 1024 = B(4) x row-tile(64) x col-chunk(4)
__global__ __launch_bounds__(256) void k_final(const float* __restrict__ ws,
                                               float* __restrict__ out) {
  __shared__ short tbh[4096];  // T hi, row-major 64x64
  __shared__ short tbl[4096];  // T lo
  const int t = threadIdx.x;
  const int gx = blockIdx.x;
  const int b = gx >> 8;
  const int rem = gx & 255;
  const int rt = rem >> 2;  // row tile 0..63
  const int ch = rem & 3;   // col chunk 0..3 (1024 cols each)
  const int r0 = rt * 64;
  const int w = t >> 6, lane = t & 63;
  const int q = lane >> 4, cl = lane & 15;
  {  // Phase A: T rows [w*16,+16) = k1_tile @ pinv, split-bf16
    const short* k1h = (const short*)(ws + K1H_OFF);
    const short* k1l = (const short*)(ws + K1L_OFF);
    const size_t ar = ((size_t)(b * Nq + r0 + w * 16 + cl)) * 64 + q * 8;
    const s16x8 ah0 = *(const s16x8*)&k1h[ar];
    const s16x8 ah1 = *(const s16x8*)&k1h[ar + 32];
    const s16x8 al0 = *(const s16x8*)&k1l[ar];
    const s16x8 al1 = *(const s16x8*)&k1l[ar + 32];
    const short* pth = (const short*)(ws + PINVTH_OFF) + b * 4096;
    const short* ptl = (const short*)(ws + PINVTL_OFF) + b * 4096;
#pragma unroll
    for (int ct = 0; ct < 4; ++ct) {
      const int br = (ct * 16 + cl) * 64 + q * 8;
      const s16x8 bh0 = *(const s16x8*)&pth[br];
      const s16x8 bh1 = *(const s16x8*)&pth[br + 32];
      const s16x8 bl0 = *(const s16x8*)&ptl[br];
      const s16x8 bl1 = *(const s16x8*)&ptl[br + 32];
      f4 acc = {0.f, 0.f, 0.f, 0.f};
      acc = __builtin_amdgcn_mfma_f32_16x16x32_bf16(ah0, bh0, acc, 0, 0, 0);
      acc = __builtin_amdgcn_mfma_f32_16x16x32_bf16(ah1, bh1, acc, 0, 0, 0);
      acc = __builtin_amdgcn_mfma_f32_16x16x32_bf16(al0, bh0, acc, 0, 0, 0);
      acc = __builtin_amdgcn_mfma_f32_16x16x32_bf16(al1, bh1, acc, 0, 0, 0);
      acc = __builtin_amdgcn_mfma_f32_16x16x32_bf16(ah0, bl0, acc, 0, 0, 0);
      acc = __builtin_amdgcn_mfma_f32_16x16x32_bf16(ah1, bl1, acc, 0, 0, 0);
#pragma unroll
      for (int i = 0; i < 4; ++i) {
        const int row = w * 16 + q * 4 + i, c = ct * 16 + cl;
        float v = acc[i];
        short h = f2bf(v);
        tbh[row * 64 + c] = h;
        tbl[row * 64 + c] = f2bf(v - bf2f(h));
      }
    }
  }
  __syncthreads();
  // Phase B: split-bf16 MFMA sweep over 1024 output cols
  const s16x8 a0h = *(const s16x8*)&tbh[(w * 16 + cl) * 64 + q * 8];
  const s16x8 a1h = *(const s16x8*)&tbh[(w * 16 + cl) * 64 + q * 8 + 32];
  const s16x8 a0l = *(const s16x8*)&tbl[(w * 16 + cl) * 64 + q * 8];
  const s16x8 a1l = *(const s16x8*)&tbl[(w * 16 + cl) * 64 + q * 8 + 32];
  const short* k3h = (const short*)(ws + K3H_OFF);
  const short* k3l = (const short*)(ws + K3L_OFF);
  const size_t boff = ((size_t)b << 18) + (size_t)(ch * 1024 + cl) * 64 + q * 8;
  const short* bph = k3h + boff;
  const short* bpl = k3l + boff;
  float* outb = out + ((size_t)(b * Nq + r0 + w * 16)) * Nq;
  s16x8 bh0 = *(const s16x8*)bph;
  s16x8 bh1 = *(const s16x8*)(bph + 32);
  s16x8 bl0 = *(const s16x8*)bpl;
  s16x8 bl1 = *(const s16x8*)(bpl + 32);
  for (int nt = 0; nt < 64; ++nt) {
    s16x8 cbh0 = bh0, cbh1 = bh1, cbl0 = bl0, cbl1 = bl1;
    if (nt < 63) {
      const short* nph = bph + (size_t)(nt + 1) * 1024;
      const short* npl = bpl + (size_t)(nt + 1) * 1024;
      bh0 = *(const s16x8*)nph;
      bh1 = *(const s16x8*)(nph + 32);
      bl0 = *(const s16x8*)npl;
      bl1 = *(const s16x8*)(npl + 32);
    }
    f4 acc = {0.f, 0.f, 0.f, 0.f};
    acc = __builtin_amdgcn_mfma_f32_16x16x32_bf16(a0h, cbh0, acc, 0, 0, 0);
    acc = __builtin_amdgcn_mfma_f32_16x16x32_bf16(a1h, cbh1, acc, 0, 0, 0);
    acc = __builtin_amdgcn_mfma_f32_16x16x32_bf16(a0l, cbh0, acc, 0, 0, 0);
    acc = __builtin_amdgcn_mfma_f32_16x16x32_bf16(a1l, cbh1, acc, 0, 0, 0);
    acc = __builtin_amdgcn_mfma_f32_16x16x32_bf16(a0h, cbl0, acc, 0, 0, 0);
    acc = __builtin_amdgcn_mfma_f32_16x16x32_bf16(a1h, cbl1, acc, 0, 0, 0);
    const int ncol = ch * 1024 + nt * 16 + cl;
    float* op = outb + (size_t)(q * 4) * Nq + ncol;
#pragma unroll
    for (int i = 0; i < 4; ++i) op[(size_t)i * Nq] = acc[i];  // row=q*4+i
  }
}

extern "C" void kernel_launch(void* const* d_in, const int* in_sizes, int n_in,
                              void* d_out, int out_size, void* d_ws,
                              size_t ws_size, hipStream_t stream) {
  const float* Q = (const float*)d_in[0];
  const float* K = (const float*)d_in[1];
  const int* iq = (const int*)d_in[2];
  const int* ik = (const int*)d_in[3];
  float* ws = (float*)d_ws;
  float* out = (float*)d_out;
  hipLaunchKernelGGL(k_main, dim3(256), dim3(256), 0, stream, Q, K, iq, ik, ws);
  hipLaunchKernelGGL(k_norm, dim3(256), dim3(256), 0, stream, ws);
  hipLaunchKernelGGL(k_final, dim3(1024), dim3(256), 0, stream, ws, out);
}